// Round 13
// baseline (50.261 us; speedup 1.0000x reference)
//
#include <hip/hip_runtime.h>

// ---------------------------------------------------------------------------
// FNNAttention (Bahdanau additive attention). B=4, Q=256, M=256, QS=KS=H=512.
// out = tanh(query@Wo1^T + P@(memory@Wo2^T) + bo),  P = softmax(logits).
// TWO dispatches:
//   1. gemm5 : LDS-staged (fp32->bf16 cvt once per block panel) bf16 MFMA
//              GEMM, 64x64 block tile / 32x32 per wave / k-chunk 128.
//              seg0: Eq=exp2(TSC*(query@Wq^T+bq))  [bf16]
//              seg1: Ek=exp2(TSC*(memory@Wk^T+bk)) [bf16]
//              seg2: Y1=query@Wo1^T+bo             [f32]
//              seg3: Z =memory@Wo2^T               [bf16]
//              block 512: mask normalization. BYTE-IDENTICAL to proven R12.
//   2. attn  : 512 blocks x 512 threads, 2 q-rows/block (2 blocks/CU so
//              co-resident blocks overlap trans-pipe phase 1 with L2-stream
//              phase 3). Same phase arithmetic as the replay-proven R11/R12
//              kernel, q-row count 4->2 (index-range change only).
// tanh(x) = 1 - 2/(exp2(TSC*x)+1), TSC = 2*log2(e). absmax regression check:
// 0.004882812 expected bit-identical.
// ---------------------------------------------------------------------------

#define B_   4
#define Q_   256
#define M_   256
#define H_   512
#define QS_  512
#define KS_  512

#define TSC 2.8853900817779268f

typedef __attribute__((ext_vector_type(8))) short bf16x8;
typedef __attribute__((ext_vector_type(4))) float f32x4;

__device__ __forceinline__ float fast_exp2(float x) { return __builtin_amdgcn_exp2f(x); }

__device__ __forceinline__ float tanh_fast(float x) {
    float e = fast_exp2(x * TSC);
    return 1.0f - 2.0f * __builtin_amdgcn_rcpf(e + 1.0f);
}

__device__ __forceinline__ unsigned short rne_bf16(float f) {
    unsigned b = __builtin_bit_cast(unsigned, f);
    return (unsigned short)((b + 0x7FFFu + ((b >> 16) & 1u)) >> 16);
}

__device__ __forceinline__ float bf2f(unsigned short u) {
    return __builtin_bit_cast(float, (unsigned)u << 16);
}

__device__ __forceinline__ bf16x8 cvt8(const float* __restrict__ p) {
    const float4 lo = *(const float4*)p;
    const float4 hi = *(const float4*)(p + 4);
    float f[8] = {lo.x, lo.y, lo.z, lo.w, hi.x, hi.y, hi.z, hi.w};
    union { bf16x8 v; unsigned short u[8]; } r;
#pragma unroll
    for (int j = 0; j < 8; ++j) r.u[j] = rne_bf16(f[j]);
    return r.v;
}

// ---------------------------------------------------------------------------
// gemm5: BYTE-IDENTICAL to proven R12.
// ---------------------------------------------------------------------------
__global__ __launch_bounds__(256) void gemm5(const float* __restrict__ query,
                                             const float* __restrict__ memory,
                                             const float* __restrict__ Wq,
                                             const float* __restrict__ Wk,
                                             const float* __restrict__ Wo,
                                             const float* __restrict__ bq,
                                             const float* __restrict__ bk,
                                             const float* __restrict__ bo,
                                             const unsigned char* __restrict__ mask,
                                             int nmask,
                                             unsigned short* __restrict__ Eqb,
                                             unsigned short* __restrict__ Ekb,
                                             float* __restrict__ Y1,
                                             unsigned short* __restrict__ Zb,
                                             int* __restrict__ maskN) {
    if (blockIdx.x == 512) {  // mask normalization (layout-detecting, r1-proven)
        __shared__ int flags[4];
        const int tid = threadIdx.x;
        int any = 0;
        for (int i = tid; i < nmask; i += 256)
            if ((i & 3) && mask[i]) any = 1;
        int wany = __any(any);
        if ((tid & 63) == 0) flags[tid >> 6] = wany ? 1 : 0;
        __syncthreads();
        const int isbool = flags[0] | flags[1] | flags[2] | flags[3];
        const int* ri = (const int*)mask;
        for (int i = tid; i < nmask; i += 256)
            maskN[i] = isbool ? (int)mask[i] : ri[i];
        return;
    }

    __shared__ unsigned short As[64][136];
    __shared__ unsigned short Ws[64][136];

    const int tid  = threadIdx.x;
    const int lane = tid & 63;
    const int wid  = tid >> 6;
    const int seg  = blockIdx.x >> 7;      // 0..3
    const int sb   = blockIdx.x & 127;
    const int bm   = sb >> 3;              // 0..15 (64-row tiles over 1024)
    const int bn   = sb & 7;               // 0..7  (64-col tiles over 512)

    const float* A;
    const float* W;
    const float* bias;
    int ldW, wko;
    if (seg == 0)      { A = query;  W = Wq; ldW = 512;  wko = 0;   bias = bq; }
    else if (seg == 1) { A = memory; W = Wk; ldW = 512;  wko = 0;   bias = bk; }
    else if (seg == 2) { A = query;  W = Wo; ldW = 1024; wko = 0;   bias = bo; }
    else               { A = memory; W = Wo; ldW = 1024; wko = 512; bias = nullptr; }

    const int wr = wid >> 1;               // 0..1 wave row
    const int wc = wid & 1;                // 0..1 wave col
    const int lr = tid >> 2;               // 0..63 stage row
    const int lq = tid & 3;                // 0..3  stage col group

    const float* Arow = &A[(bm * 64 + lr) * 512];
    const float* Wrow = &W[(bn * 64 + lr) * ldW + wko];

    f32x4 acc00 = {0,0,0,0}, acc01 = {0,0,0,0}, acc10 = {0,0,0,0}, acc11 = {0,0,0,0};

    for (int kt = 0; kt < 512; kt += 128) {
        // ---- stage 128-k chunk: fp32 -> bf16 into LDS (cvt once per panel) ----
#pragma unroll
        for (int j = 0; j < 4; ++j) {
            const int c8 = (lq + 4 * j) * 8;   // 8-elem blocks, 4 threads/row
            *(bf16x8*)&As[lr][c8] = cvt8(&Arow[kt + c8]);
            *(bf16x8*)&Ws[lr][c8] = cvt8(&Wrow[kt + c8]);
        }
        __syncthreads();
        // ---- compute: 4 k-steps of 32 ----
#pragma unroll
        for (int ks = 0; ks < 4; ++ks) {
            const int kk = ks * 32 + (lane >> 4) * 8;
            bf16x8 a0 = *(const bf16x8*)&As[wr * 32 + (lane & 15)][kk];
            bf16x8 a1 = *(const bf16x8*)&As[wr * 32 + 16 + (lane & 15)][kk];
            bf16x8 b0 = *(const bf16x8*)&Ws[wc * 32 + (lane & 15)][kk];
            bf16x8 b1 = *(const bf16x8*)&Ws[wc * 32 + 16 + (lane & 15)][kk];
            acc00 = __builtin_amdgcn_mfma_f32_16x16x32_bf16(a0, b0, acc00, 0, 0, 0);
            acc01 = __builtin_amdgcn_mfma_f32_16x16x32_bf16(a0, b1, acc01, 0, 0, 0);
            acc10 = __builtin_amdgcn_mfma_f32_16x16x32_bf16(a1, b0, acc10, 0, 0, 0);
            acc11 = __builtin_amdgcn_mfma_f32_16x16x32_bf16(a1, b1, acc11, 0, 0, 0);
        }
        __syncthreads();
    }

    const int col = bn * 64 + wc * 32 + (lane & 15);
    const int r0  = bm * 64 + wr * 32 + (lane >> 4) * 4;
    const float bv0 = bias ? bias[col] : 0.f;
    const float bv1 = bias ? bias[col + 16] : 0.f;
    if (seg < 2) {
        unsigned short* E = (seg == 0) ? Eqb : Ekb;
#pragma unroll
        for (int j = 0; j < 4; ++j) {
            E[(r0 + j) * 512 + col]           = rne_bf16(fast_exp2(TSC * (acc00[j] + bv0)));
            E[(r0 + j) * 512 + col + 16]      = rne_bf16(fast_exp2(TSC * (acc01[j] + bv1)));
            E[(r0 + 16 + j) * 512 + col]      = rne_bf16(fast_exp2(TSC * (acc10[j] + bv0)));
            E[(r0 + 16 + j) * 512 + col + 16] = rne_bf16(fast_exp2(TSC * (acc11[j] + bv1)));
        }
    } else if (seg == 2) {
#pragma unroll
        for (int j = 0; j < 4; ++j) {
            Y1[(r0 + j) * 512 + col]           = acc00[j] + bv0;
            Y1[(r0 + j) * 512 + col + 16]      = acc01[j] + bv1;
            Y1[(r0 + 16 + j) * 512 + col]      = acc10[j] + bv0;
            Y1[(r0 + 16 + j) * 512 + col + 16] = acc11[j] + bv1;
        }
    } else {
#pragma unroll
        for (int j = 0; j < 4; ++j) {
            Zb[(r0 + j) * 512 + col]           = rne_bf16(acc00[j]);
            Zb[(r0 + j) * 512 + col + 16]      = rne_bf16(acc01[j]);
            Zb[(r0 + 16 + j) * 512 + col]      = rne_bf16(acc10[j]);
            Zb[(r0 + 16 + j) * 512 + col + 16] = rne_bf16(acc11[j]);
        }
    }
}

// ---------------------------------------------------------------------------
// attn: logits + softmax + final output. Block = (b, 2 q-rows), 512 threads
// (8 waves), grid = 128 x 4 = 512 blocks (2 blocks/CU). Phase arithmetic
// identical to the replay-proven R11/R12 kernel; q-rows/block 4 -> 2.
// ---------------------------------------------------------------------------
__global__ __launch_bounds__(512) void attn_fused(const int* __restrict__ maskN,
                                                  const unsigned short* __restrict__ Eqb,
                                                  const unsigned short* __restrict__ Ekb,
                                                  const float* __restrict__ Wl,
                                                  const float* __restrict__ bl,
                                                  const float* __restrict__ Y1,
                                                  const unsigned short* __restrict__ Zb,
                                                  float* __restrict__ wout,
                                                  float* __restrict__ out) {
    const int b = blockIdx.y;
    const int q0 = blockIdx.x * 2;
    const int tid = threadIdx.x;
    const int wid = tid >> 6;
    const int lane = tid & 63;

    __shared__ float slog[2][M_];
    __shared__ float swt[2][M_];
    __shared__ int s_list[M_];
    __shared__ int s_base[4];
    __shared__ int s_cnt;
    __shared__ int s_allmask;

    // ---- phase 0: compact unmasked m list (waves 0-3, same as proven) ----
    int msk_ = 1, prefix_ = 0;
    if (tid < 256) {
        msk_ = maskN[(b << 8) + tid];
        unsigned long long vote = __ballot(msk_ == 0);
        prefix_ = __popcll(vote & ((1ull << lane) - 1ull));
        if (lane == 0) s_base[wid] = __popcll(vote);
    }
    __syncthreads();
    if (tid == 0) {
        int s = 0;
#pragma unroll
        for (int i = 0; i < 4; ++i) { int c = s_base[i]; s_base[i] = s; s += c; }
        s_cnt = s;
    }
    __syncthreads();
    if (tid < 256 && !msk_) s_list[s_base[wid] + prefix_] = tid;

    // per-lane register slices (Eq already exponentiated, bf16)
    float qreg[2][8], wlr[8];
#pragma unroll
    for (int qi = 0; qi < 2; ++qi) {
        union { bf16x8 v; unsigned short u[8]; } qv;
        qv.v = *(const bf16x8*)&Eqb[((b << 8) + (q0 + qi)) * H_ + lane * 8];
#pragma unroll
        for (int h = 0; h < 8; ++h) qreg[qi][h] = bf2f(qv.u[h]);
    }
    *(float4*)&wlr[0] = *(const float4*)&Wl[lane * 8];
    *(float4*)&wlr[4] = *(const float4*)&Wl[lane * 8 + 4];
    const float bl0 = bl[0];

    float sumWL = wlr[0] + wlr[1] + wlr[2] + wlr[3] + wlr[4] + wlr[5] + wlr[6] + wlr[7];
#pragma unroll
    for (int off = 32; off; off >>= 1) sumWL += __shfl_xor(sumWL, off, 64);

    __syncthreads();
    const int cnt = s_cnt;

    // ---- phase 1: logits over compacted list (1 rcp per element) ----
    for (int idx = wid; idx < cnt; idx += 8) {
        const int m = s_list[idx];
        union { bf16x8 v; unsigned short u[8]; } kv;
        kv.v = *(const bf16x8*)&Ekb[((b << 8) + m) * H_ + lane * 8];
        float acc[2] = {0.f, 0.f};
#pragma unroll
        for (int h = 0; h < 8; ++h) {
            const float ek = bf2f(kv.u[h]);
            const float wv = wlr[h];
#pragma unroll
            for (int qi = 0; qi < 2; ++qi) {
                const float e = qreg[qi][h] * ek;
                const float r = __builtin_amdgcn_rcpf(e + 1.0f);
                acc[qi] = fmaf(wv, r, acc[qi]);
            }
        }
#pragma unroll
        for (int qi = 0; qi < 2; ++qi) {
            float v = acc[qi];
#pragma unroll
            for (int off = 32; off; off >>= 1) v += __shfl_xor(v, off, 64);
            if (lane == 0) slog[qi][m] = sumWL - 2.0f * v + bl0;
        }
    }
    __syncthreads();

    // ---- phase 2: softmax (wave wid < 2 owns row q0+wid) ----
    if (wid < 2) {
        const int qi = wid;
        float x[4];
        int mk[4];
#pragma unroll
        for (int j = 0; j < 4; ++j) {
            const int m = lane * 4 + j;
            mk[j] = maskN[(b << 8) + m];
            x[j] = mk[j] ? -1e30f : slog[qi][m];
        }
        float mx = fmaxf(fmaxf(x[0], x[1]), fmaxf(x[2], x[3]));
#pragma unroll
        for (int off = 32; off; off >>= 1) mx = fmaxf(mx, __shfl_xor(mx, off, 64));
        float e[4], s = 0.f;
#pragma unroll
        for (int j = 0; j < 4; ++j) {
            e[j] = mk[j] ? 0.f : fast_exp2((x[j] - mx) * 1.4426950408889634f);
            s += e[j];
        }
#pragma unroll
        for (int off = 32; off; off >>= 1) s += __shfl_xor(s, off, 64);
        float w4[4];
        if (s > 0.f) {
            const float inv = 1.0f / s;
#pragma unroll
            for (int j = 0; j < 4; ++j) w4[j] = e[j] * inv;
        } else {
#pragma unroll
            for (int j = 0; j < 4; ++j) w4[j] = 1.0f / (float)M_;
        }
#pragma unroll
        for (int j = 0; j < 4; ++j) swt[qi][lane * 4 + j] = w4[j];
        *(float4*)&wout[((b << 8) + (q0 + qi)) * M_ + lane * 4] = *(const float4*)w4;
        if (tid == 0) s_allmask = (s <= 0.f) ? 1 : 0;
    }
    __syncthreads();

    // ---- phase 3: out[q][d] = tanh(Y1[q][d] + sum_m swt[q][m]*Z[b][m][d]),
    // all 512 threads, 2 q-rows ----
    {
        const int am = s_allmask;
        float a0 = 0.f, a1 = 0.f;
        const unsigned short* Zrow = &Zb[((b << 8)) * QS_ + tid];
        if (!am) {
            for (int idx = 0; idx < cnt; ++idx) {
                const int m = s_list[idx];
                const float zv = bf2f(Zrow[m * QS_]);
                a0 = fmaf(swt[0][m], zv, a0);
                a1 = fmaf(swt[1][m], zv, a1);
            }
        } else {
            for (int m = 0; m < M_; ++m) {
                const float zv = bf2f(Zrow[m * QS_]);
                a0 = fmaf(swt[0][m], zv, a0);
                a1 = fmaf(swt[1][m], zv, a1);
            }
        }
        const int r0 = (b << 8) + q0;
        out[r0 * QS_ + tid]       = tanh_fast(Y1[r0 * QS_ + tid] + a0);
        out[(r0 + 1) * QS_ + tid] = tanh_fast(Y1[(r0 + 1) * QS_ + tid] + a1);
    }
}

// ---------------------------------------------------------------------------
extern "C" void kernel_launch(void* const* d_in, const int* in_sizes, int n_in,
                              void* d_out, int out_size, void* d_ws, size_t ws_size,
                              hipStream_t stream) {
    const float* query  = (const float*)d_in[0];
    const float* memory = (const float*)d_in[1];
    const void*  mask   = d_in[2];
    const float* Wk = (const float*)d_in[3];
    const float* bk = (const float*)d_in[4];
    const float* Wq = (const float*)d_in[5];
    const float* bq = (const float*)d_in[6];
    const float* Wl = (const float*)d_in[7];
    const float* bl = (const float*)d_in[8];
    const float* Wo = (const float*)d_in[9];
    const float* bo = (const float*)d_in[10];

    float* out  = (float*)d_out;                 // [4,256,512]
    float* wout = out + B_ * Q_ * QS_;           // [4,256,256]

    float* ws = (float*)d_ws;
    float*          Y1    = ws;                              // 524288 f32
    unsigned short* Eqb   = (unsigned short*)(ws + 524288);  // 524288 bf16
    unsigned short* Ekb   = (unsigned short*)(ws + 786432);  // 524288 bf16
    unsigned short* Zb    = (unsigned short*)(ws + 1048576); // 524288 bf16
    int*            maskN = (int*)(ws + 1310720);            // 1024 int

    hipLaunchKernelGGL(gemm5, dim3(513), dim3(256), 0, stream,
                       query, memory, Wq, Wk, Wo, bq, bk, bo,
                       (const unsigned char*)mask, in_sizes[2],
                       Eqb, Ekb, Y1, Zb, maskN);
    hipLaunchKernelGGL(attn_fused, dim3(Q_ / 2, B_), dim3(512), 0, stream,
                       maskN, Eqb, Ekb, Wl, bl, Y1, Zb, wout, out);
}

// Round 14
// 47.890 us; speedup vs baseline: 1.0495x; 1.0495x over previous
//
#include <hip/hip_runtime.h>

// ---------------------------------------------------------------------------
// FNNAttention (Bahdanau additive attention). B=4, Q=256, M=256, QS=KS=H=512.
// out = tanh(query@Wo1^T + P@(memory@Wo2^T) + bo),  P = softmax(logits).
// PROVEN R12 CONFIGURATION (47.9 us, absmax 0.004882812) — exact revert.
// TWO dispatches:
//   1. gemm5 : LDS-staged (fp32->bf16 cvt once per block panel) bf16 MFMA
//              GEMM, 64x64 block tile / 32x32 per wave / k-chunk 128.
//              seg0: Eq=exp2(TSC*(query@Wq^T+bq))  [bf16]
//              seg1: Ek=exp2(TSC*(memory@Wk^T+bk)) [bf16]
//              seg2: Y1=query@Wo1^T+bo             [f32]
//              seg3: Z =memory@Wo2^T               [bf16]
//              block 512: mask normalization (layout-detecting).
//   2. attn  : 256 blocks x 1024 threads, 4 q-rows/block. logits via
//              rcp(Eq*Ek+1) (compacted unmasked-m list), softmax,
//              weights -> wout, out = tanh(Y1 + P@Z).
// tanh(x) = 1 - 2/(exp2(TSC*x)+1), TSC = 2*log2(e).
// ---------------------------------------------------------------------------

#define B_   4
#define Q_   256
#define M_   256
#define H_   512
#define QS_  512
#define KS_  512

#define TSC 2.8853900817779268f

typedef __attribute__((ext_vector_type(8))) short bf16x8;
typedef __attribute__((ext_vector_type(4))) float f32x4;

__device__ __forceinline__ float fast_exp2(float x) { return __builtin_amdgcn_exp2f(x); }

__device__ __forceinline__ float tanh_fast(float x) {
    float e = fast_exp2(x * TSC);
    return 1.0f - 2.0f * __builtin_amdgcn_rcpf(e + 1.0f);
}

__device__ __forceinline__ unsigned short rne_bf16(float f) {
    unsigned b = __builtin_bit_cast(unsigned, f);
    return (unsigned short)((b + 0x7FFFu + ((b >> 16) & 1u)) >> 16);
}

__device__ __forceinline__ float bf2f(unsigned short u) {
    return __builtin_bit_cast(float, (unsigned)u << 16);
}

__device__ __forceinline__ bf16x8 cvt8(const float* __restrict__ p) {
    const float4 lo = *(const float4*)p;
    const float4 hi = *(const float4*)(p + 4);
    float f[8] = {lo.x, lo.y, lo.z, lo.w, hi.x, hi.y, hi.z, hi.w};
    union { bf16x8 v; unsigned short u[8]; } r;
#pragma unroll
    for (int j = 0; j < 8; ++j) r.u[j] = rne_bf16(f[j]);
    return r.v;
}

// ---------------------------------------------------------------------------
// gemm5: four batched NT-GEMMs, LDS-staged with in-block fp32->bf16 cvt.
// Block = 256 threads (4 waves, 2x2 of 32x32 tiles), block tile 64x64,
// k-chunk 128 (4 chunks). LDS [64][136] bf16 per operand (pad 8 -> 2-way
// bank aliasing on ds_read_b128, free). grid = 512 gemm blocks + 1 mask.
// Fragment map: A/B lane l -> row/col = l&15, k = kt + (l>>4)*8 + j.
// D: reg j -> row (l>>4)*4+j, col l&15  [measured m89].
// ---------------------------------------------------------------------------
__global__ __launch_bounds__(256) void gemm5(const float* __restrict__ query,
                                             const float* __restrict__ memory,
                                             const float* __restrict__ Wq,
                                             const float* __restrict__ Wk,
                                             const float* __restrict__ Wo,
                                             const float* __restrict__ bq,
                                             const float* __restrict__ bk,
                                             const float* __restrict__ bo,
                                             const unsigned char* __restrict__ mask,
                                             int nmask,
                                             unsigned short* __restrict__ Eqb,
                                             unsigned short* __restrict__ Ekb,
                                             float* __restrict__ Y1,
                                             unsigned short* __restrict__ Zb,
                                             int* __restrict__ maskN) {
    if (blockIdx.x == 512) {  // mask normalization (layout-detecting, r1-proven)
        __shared__ int flags[4];
        const int tid = threadIdx.x;
        int any = 0;
        for (int i = tid; i < nmask; i += 256)
            if ((i & 3) && mask[i]) any = 1;
        int wany = __any(any);
        if ((tid & 63) == 0) flags[tid >> 6] = wany ? 1 : 0;
        __syncthreads();
        const int isbool = flags[0] | flags[1] | flags[2] | flags[3];
        const int* ri = (const int*)mask;
        for (int i = tid; i < nmask; i += 256)
            maskN[i] = isbool ? (int)mask[i] : ri[i];
        return;
    }

    __shared__ unsigned short As[64][136];
    __shared__ unsigned short Ws[64][136];

    const int tid  = threadIdx.x;
    const int lane = tid & 63;
    const int wid  = tid >> 6;
    const int seg  = blockIdx.x >> 7;      // 0..3
    const int sb   = blockIdx.x & 127;
    const int bm   = sb >> 3;              // 0..15 (64-row tiles over 1024)
    const int bn   = sb & 7;               // 0..7  (64-col tiles over 512)

    const float* A;
    const float* W;
    const float* bias;
    int ldW, wko;
    if (seg == 0)      { A = query;  W = Wq; ldW = 512;  wko = 0;   bias = bq; }
    else if (seg == 1) { A = memory; W = Wk; ldW = 512;  wko = 0;   bias = bk; }
    else if (seg == 2) { A = query;  W = Wo; ldW = 1024; wko = 0;   bias = bo; }
    else               { A = memory; W = Wo; ldW = 1024; wko = 512; bias = nullptr; }

    const int wr = wid >> 1;               // 0..1 wave row
    const int wc = wid & 1;                // 0..1 wave col
    const int lr = tid >> 2;               // 0..63 stage row
    const int lq = tid & 3;                // 0..3  stage col group

    const float* Arow = &A[(bm * 64 + lr) * 512];
    const float* Wrow = &W[(bn * 64 + lr) * ldW + wko];

    f32x4 acc00 = {0,0,0,0}, acc01 = {0,0,0,0}, acc10 = {0,0,0,0}, acc11 = {0,0,0,0};

    for (int kt = 0; kt < 512; kt += 128) {
        // ---- stage 128-k chunk: fp32 -> bf16 into LDS (cvt once per panel) ----
#pragma unroll
        for (int j = 0; j < 4; ++j) {
            const int c8 = (lq + 4 * j) * 8;   // 8-elem blocks, 4 threads/row
            *(bf16x8*)&As[lr][c8] = cvt8(&Arow[kt + c8]);
            *(bf16x8*)&Ws[lr][c8] = cvt8(&Wrow[kt + c8]);
        }
        __syncthreads();
        // ---- compute: 4 k-steps of 32 ----
#pragma unroll
        for (int ks = 0; ks < 4; ++ks) {
            const int kk = ks * 32 + (lane >> 4) * 8;
            bf16x8 a0 = *(const bf16x8*)&As[wr * 32 + (lane & 15)][kk];
            bf16x8 a1 = *(const bf16x8*)&As[wr * 32 + 16 + (lane & 15)][kk];
            bf16x8 b0 = *(const bf16x8*)&Ws[wc * 32 + (lane & 15)][kk];
            bf16x8 b1 = *(const bf16x8*)&Ws[wc * 32 + 16 + (lane & 15)][kk];
            acc00 = __builtin_amdgcn_mfma_f32_16x16x32_bf16(a0, b0, acc00, 0, 0, 0);
            acc01 = __builtin_amdgcn_mfma_f32_16x16x32_bf16(a0, b1, acc01, 0, 0, 0);
            acc10 = __builtin_amdgcn_mfma_f32_16x16x32_bf16(a1, b0, acc10, 0, 0, 0);
            acc11 = __builtin_amdgcn_mfma_f32_16x16x32_bf16(a1, b1, acc11, 0, 0, 0);
        }
        __syncthreads();
    }

    const int col = bn * 64 + wc * 32 + (lane & 15);
    const int r0  = bm * 64 + wr * 32 + (lane >> 4) * 4;
    const float bv0 = bias ? bias[col] : 0.f;
    const float bv1 = bias ? bias[col + 16] : 0.f;
    if (seg < 2) {
        unsigned short* E = (seg == 0) ? Eqb : Ekb;
#pragma unroll
        for (int j = 0; j < 4; ++j) {
            E[(r0 + j) * 512 + col]           = rne_bf16(fast_exp2(TSC * (acc00[j] + bv0)));
            E[(r0 + j) * 512 + col + 16]      = rne_bf16(fast_exp2(TSC * (acc01[j] + bv1)));
            E[(r0 + 16 + j) * 512 + col]      = rne_bf16(fast_exp2(TSC * (acc10[j] + bv0)));
            E[(r0 + 16 + j) * 512 + col + 16] = rne_bf16(fast_exp2(TSC * (acc11[j] + bv1)));
        }
    } else if (seg == 2) {
#pragma unroll
        for (int j = 0; j < 4; ++j) {
            Y1[(r0 + j) * 512 + col]           = acc00[j] + bv0;
            Y1[(r0 + j) * 512 + col + 16]      = acc01[j] + bv1;
            Y1[(r0 + 16 + j) * 512 + col]      = acc10[j] + bv0;
            Y1[(r0 + 16 + j) * 512 + col + 16] = acc11[j] + bv1;
        }
    } else {
#pragma unroll
        for (int j = 0; j < 4; ++j) {
            Zb[(r0 + j) * 512 + col]           = rne_bf16(acc00[j]);
            Zb[(r0 + j) * 512 + col + 16]      = rne_bf16(acc01[j]);
            Zb[(r0 + 16 + j) * 512 + col]      = rne_bf16(acc10[j]);
            Zb[(r0 + 16 + j) * 512 + col + 16] = rne_bf16(acc11[j]);
        }
    }
}

// ---------------------------------------------------------------------------
// attn: logits + softmax + final output. Block = (b, 4 q-rows), 1024 threads.
// BYTE-IDENTICAL to the replay-proven R11/R12 kernel.
// ---------------------------------------------------------------------------
__global__ __launch_bounds__(1024) void attn_fused(const int* __restrict__ maskN,
                                                   const unsigned short* __restrict__ Eqb,
                                                   const unsigned short* __restrict__ Ekb,
                                                   const float* __restrict__ Wl,
                                                   const float* __restrict__ bl,
                                                   const float* __restrict__ Y1,
                                                   const unsigned short* __restrict__ Zb,
                                                   float* __restrict__ wout,
                                                   float* __restrict__ out) {
    const int b = blockIdx.y;
    const int q0 = blockIdx.x * 4;
    const int tid = threadIdx.x;
    const int wid = tid >> 6;
    const int lane = tid & 63;

    __shared__ float slog[4][M_];
    __shared__ float swt[4][M_];
    __shared__ int s_list[M_];
    __shared__ int s_base[4];
    __shared__ int s_cnt;
    __shared__ int s_allmask;

    // ---- phase 0: compact unmasked m list ----
    int msk_ = 1, prefix_ = 0;
    if (tid < 256) {
        msk_ = maskN[(b << 8) + tid];
        unsigned long long vote = __ballot(msk_ == 0);
        prefix_ = __popcll(vote & ((1ull << lane) - 1ull));
        if (lane == 0) s_base[wid] = __popcll(vote);
    }
    __syncthreads();
    if (tid == 0) {
        int s = 0;
#pragma unroll
        for (int i = 0; i < 4; ++i) { int c = s_base[i]; s_base[i] = s; s += c; }
        s_cnt = s;
    }
    __syncthreads();
    if (tid < 256 && !msk_) s_list[s_base[wid] + prefix_] = tid;

    // per-lane register slices (Eq already exponentiated, bf16)
    float qreg[4][8], wlr[8];
#pragma unroll
    for (int qi = 0; qi < 4; ++qi) {
        union { bf16x8 v; unsigned short u[8]; } qv;
        qv.v = *(const bf16x8*)&Eqb[((b << 8) + (q0 + qi)) * H_ + lane * 8];
#pragma unroll
        for (int h = 0; h < 8; ++h) qreg[qi][h] = bf2f(qv.u[h]);
    }
    *(float4*)&wlr[0] = *(const float4*)&Wl[lane * 8];
    *(float4*)&wlr[4] = *(const float4*)&Wl[lane * 8 + 4];
    const float bl0 = bl[0];

    float sumWL = wlr[0] + wlr[1] + wlr[2] + wlr[3] + wlr[4] + wlr[5] + wlr[6] + wlr[7];
#pragma unroll
    for (int off = 32; off; off >>= 1) sumWL += __shfl_xor(sumWL, off, 64);

    __syncthreads();
    const int cnt = s_cnt;

    // ---- phase 1: logits over compacted list (1 rcp per element) ----
    for (int idx = wid; idx < cnt; idx += 16) {
        const int m = s_list[idx];
        union { bf16x8 v; unsigned short u[8]; } kv;
        kv.v = *(const bf16x8*)&Ekb[((b << 8) + m) * H_ + lane * 8];
        float acc[4] = {0.f, 0.f, 0.f, 0.f};
#pragma unroll
        for (int h = 0; h < 8; ++h) {
            const float ek = bf2f(kv.u[h]);
            const float wv = wlr[h];
#pragma unroll
            for (int qi = 0; qi < 4; ++qi) {
                const float e = qreg[qi][h] * ek;
                const float r = __builtin_amdgcn_rcpf(e + 1.0f);
                acc[qi] = fmaf(wv, r, acc[qi]);
            }
        }
#pragma unroll
        for (int qi = 0; qi < 4; ++qi) {
            float v = acc[qi];
#pragma unroll
            for (int off = 32; off; off >>= 1) v += __shfl_xor(v, off, 64);
            if (lane == 0) slog[qi][m] = sumWL - 2.0f * v + bl0;
        }
    }
    __syncthreads();

    // ---- phase 2: softmax (wave wid < 4 owns row q0+wid) ----
    if (wid < 4) {
        const int qi = wid;
        float x[4];
        int mk[4];
#pragma unroll
        for (int j = 0; j < 4; ++j) {
            const int m = lane * 4 + j;
            mk[j] = maskN[(b << 8) + m];
            x[j] = mk[j] ? -1e30f : slog[qi][m];
        }
        float mx = fmaxf(fmaxf(x[0], x[1]), fmaxf(x[2], x[3]));
#pragma unroll
        for (int off = 32; off; off >>= 1) mx = fmaxf(mx, __shfl_xor(mx, off, 64));
        float e[4], s = 0.f;
#pragma unroll
        for (int j = 0; j < 4; ++j) {
            e[j] = mk[j] ? 0.f : fast_exp2((x[j] - mx) * 1.4426950408889634f);
            s += e[j];
        }
#pragma unroll
        for (int off = 32; off; off >>= 1) s += __shfl_xor(s, off, 64);
        float w4[4];
        if (s > 0.f) {
            const float inv = 1.0f / s;
#pragma unroll
            for (int j = 0; j < 4; ++j) w4[j] = e[j] * inv;
        } else {
#pragma unroll
            for (int j = 0; j < 4; ++j) w4[j] = 1.0f / (float)M_;
        }
#pragma unroll
        for (int j = 0; j < 4; ++j) swt[qi][lane * 4 + j] = w4[j];
        *(float4*)&wout[((b << 8) + (q0 + qi)) * M_ + lane * 4] = *(const float4*)w4;
        if (tid == 0) s_allmask = (s <= 0.f) ? 1 : 0;
    }
    __syncthreads();

    // ---- phase 3: out[q][d] = tanh(Y1[q][d] + sum_m swt[q][m]*Z[b][m][d]) ----
    if (tid < QS_) {
        const int am = s_allmask;
        float a[4] = {0.f, 0.f, 0.f, 0.f};
        const unsigned short* Zrow = &Zb[((b << 8)) * QS_ + tid];
        if (!am) {
            for (int idx = 0; idx < cnt; ++idx) {
                const int m = s_list[idx];
                const float zv = bf2f(Zrow[m * QS_]);
#pragma unroll
                for (int qi = 0; qi < 4; ++qi) a[qi] = fmaf(swt[qi][m], zv, a[qi]);
            }
        } else {
            for (int m = 0; m < M_; ++m) {
                const float zv = bf2f(Zrow[m * QS_]);
#pragma unroll
                for (int qi = 0; qi < 4; ++qi) a[qi] = fmaf(swt[qi][m], zv, a[qi]);
            }
        }
#pragma unroll
        for (int qi = 0; qi < 4; ++qi) {
            const int r = (b << 8) + q0 + qi;
            out[r * QS_ + tid] = tanh_fast(Y1[r * QS_ + tid] + a[qi]);
        }
    }
}

// ---------------------------------------------------------------------------
extern "C" void kernel_launch(void* const* d_in, const int* in_sizes, int n_in,
                              void* d_out, int out_size, void* d_ws, size_t ws_size,
                              hipStream_t stream) {
    const float* query  = (const float*)d_in[0];
    const float* memory = (const float*)d_in[1];
    const void*  mask   = d_in[2];
    const float* Wk = (const float*)d_in[3];
    const float* bk = (const float*)d_in[4];
    const float* Wq = (const float*)d_in[5];
    const float* bq = (const float*)d_in[6];
    const float* Wl = (const float*)d_in[7];
    const float* bl = (const float*)d_in[8];
    const float* Wo = (const float*)d_in[9];
    const float* bo = (const float*)d_in[10];

    float* out  = (float*)d_out;                 // [4,256,512]
    float* wout = out + B_ * Q_ * QS_;           // [4,256,256]

    float* ws = (float*)d_ws;
    float*          Y1    = ws;                              // 524288 f32
    unsigned short* Eqb   = (unsigned short*)(ws + 524288);  // 524288 bf16
    unsigned short* Ekb   = (unsigned short*)(ws + 786432);  // 524288 bf16
    unsigned short* Zb    = (unsigned short*)(ws + 1048576); // 524288 bf16
    int*            maskN = (int*)(ws + 1310720);            // 1024 int

    hipLaunchKernelGGL(gemm5, dim3(513), dim3(256), 0, stream,
                       query, memory, Wq, Wk, Wo, bq, bk, bo,
                       (const unsigned char*)mask, in_sizes[2],
                       Eqb, Ekb, Y1, Zb, maskN);
    hipLaunchKernelGGL(attn_fused, dim3(Q_ / 4, B_), dim3(1024), 0, stream,
                       maskN, Eqb, Ekb, Wl, bl, Y1, Zb, wout, out);
}